// Round 1
// baseline (250.075 us; speedup 1.0000x reference)
//
#include <hip/hip_runtime.h>
#include <hip/hip_cooperative_groups.h>

namespace cg = cooperative_groups;

#define LOG2E 1.44269504088896340736f

__device__ __forceinline__ float fast_exp2(float x) {
#if __has_builtin(__builtin_amdgcn_exp2f)
    return __builtin_amdgcn_exp2f(x);
#else
    return exp2f(x);
#endif
}

// ---------------------------------------------------------------------------
// Single cooperative kernel, 3 phases separated by grid.sync():
//   Phase 1: fused QKV projection with transposed outputs (bid<256: Q path,
//            bid>=256: KV path) — math identical to the previous proj_kernel.
//   Phase 2: attention, head_dim==1 — identical to previous attn_kernel.
//   Phase 3: out = O @ Wo + bo, re-split over all 512 blocks (4 rows each).
// Rationale: removes two graph-node boundaries (drain+dispatch) and keeps all
// per-phase geometry/occupancy identical (2 blocks/CU, 8 waves/CU).
// LDS is a single 32 KB arena re-used per phase (64 KB/CU at 2 blocks/CU).
// ---------------------------------------------------------------------------
__global__ __launch_bounds__(256, 2) void fused_kernel(
    const float* __restrict__ x, const float* __restrict__ emb,
    const float* __restrict__ Wq, const float* __restrict__ Wk,
    const float* __restrict__ Wv, const float* __restrict__ Wo,
    const float* __restrict__ bo, float* __restrict__ out,
    float* __restrict__ qT, float* __restrict__ kT,
    float* __restrict__ vT, float* __restrict__ O)
{
    __shared__ __align__(16) float smem[8192];   // 32 KB arena
    const int t   = threadIdx.x;
    const int bid = blockIdx.x;
    cg::grid_group grid = cg::this_grid();

    // ---------------- Phase 1: QKV projection ----------------
    {
        float* sx   = smem;          // 8 rows x 512
        float* sred = smem + 4096;   // partial-sum reduction buffer
        const bool isQ = (bid < 256);
        const int rb  = isQ ? bid : (bid - 256);

        const float* src = (isQ ? x : emb) + (size_t)rb * 8 * 512;
        #pragma unroll
        for (int i = 0; i < 16; ++i) sx[i * 256 + t] = src[i * 256 + t];
        __syncthreads();

        const int b  = rb >> 7;          // rows rb*8 -> batch
        const int q0 = (rb << 3) & 1023; // seq offset

        if (isQ) {
            const int cp = (t & 31) * 2;
            const int g  = t >> 5;
            const int d0 = g * 64;
            float acc0[8], acc1[8];
            #pragma unroll
            for (int r = 0; r < 8; ++r) { acc0[r] = 0.f; acc1[r] = 0.f; }
            for (int dd = 0; dd < 64; dd += 4) {
                const int d = d0 + dd;
                float2 w0 = *(const float2*)&Wq[(d + 0) * 64 + cp];
                float2 w1 = *(const float2*)&Wq[(d + 1) * 64 + cp];
                float2 w2 = *(const float2*)&Wq[(d + 2) * 64 + cp];
                float2 w3 = *(const float2*)&Wq[(d + 3) * 64 + cp];
                #pragma unroll
                for (int r = 0; r < 8; ++r) {
                    float4 xv = *(const float4*)&sx[r * 512 + d];
                    acc0[r] = fmaf(xv.x, w0.x, acc0[r]); acc1[r] = fmaf(xv.x, w0.y, acc1[r]);
                    acc0[r] = fmaf(xv.y, w1.x, acc0[r]); acc1[r] = fmaf(xv.y, w1.y, acc1[r]);
                    acc0[r] = fmaf(xv.z, w2.x, acc0[r]); acc1[r] = fmaf(xv.z, w2.y, acc1[r]);
                    acc0[r] = fmaf(xv.w, w3.x, acc0[r]); acc1[r] = fmaf(xv.w, w3.y, acc1[r]);
                }
            }
            #pragma unroll
            for (int r = 0; r < 8; ++r)
                *(float2*)&sred[g * 512 + r * 64 + cp] = make_float2(acc0[r], acc1[r]);
            __syncthreads();
            #pragma unroll
            for (int p = 0; p < 2; ++p) {
                int idx = p * 256 + t;
                int r = idx >> 6, h = idx & 63;
                float s = 0.f;
                #pragma unroll
                for (int g2 = 0; g2 < 8; ++g2) s += sred[g2 * 512 + r * 64 + h];
                qT[(size_t)(b * 64 + h) * 1024 + q0 + r] = s;
            }
        } else {
            const int cp = (t & 63) * 2;
            const int g  = t >> 6;
            const int d0 = g * 128;
            const float* Wsel = (cp < 64) ? (Wk + cp) : (Wv + (cp - 64));
            float acc0[8], acc1[8];
            #pragma unroll
            for (int r = 0; r < 8; ++r) { acc0[r] = 0.f; acc1[r] = 0.f; }
            for (int dd = 0; dd < 128; dd += 4) {
                const int d = d0 + dd;
                float2 w0 = *(const float2*)&Wsel[(d + 0) * 64];
                float2 w1 = *(const float2*)&Wsel[(d + 1) * 64];
                float2 w2 = *(const float2*)&Wsel[(d + 2) * 64];
                float2 w3 = *(const float2*)&Wsel[(d + 3) * 64];
                #pragma unroll
                for (int r = 0; r < 8; ++r) {
                    float4 xv = *(const float4*)&sx[r * 512 + d];
                    acc0[r] = fmaf(xv.x, w0.x, acc0[r]); acc1[r] = fmaf(xv.x, w0.y, acc1[r]);
                    acc0[r] = fmaf(xv.y, w1.x, acc0[r]); acc1[r] = fmaf(xv.y, w1.y, acc1[r]);
                    acc0[r] = fmaf(xv.z, w2.x, acc0[r]); acc1[r] = fmaf(xv.z, w2.y, acc1[r]);
                    acc0[r] = fmaf(xv.w, w3.x, acc0[r]); acc1[r] = fmaf(xv.w, w3.y, acc1[r]);
                }
            }
            #pragma unroll
            for (int r = 0; r < 8; ++r)
                *(float2*)&sred[g * 1024 + r * 128 + cp] = make_float2(acc0[r], acc1[r]);
            __syncthreads();
            #pragma unroll
            for (int p = 0; p < 4; ++p) {
                int idx = p * 256 + t;
                int r = idx >> 7, c = idx & 127;
                float s = 0.f;
                #pragma unroll
                for (int g2 = 0; g2 < 4; ++g2) s += sred[g2 * 1024 + r * 128 + c];
                if (c < 64) kT[(size_t)(b * 64 + c) * 1024 + q0 + r] = s;
                else        vT[(size_t)(b * 64 + (c - 64)) * 1024 + q0 + r] = s;
            }
        }
    }

    grid.sync();   // qT/kT/vT visible device-wide

    // ---------------- Phase 2: attention ----------------
    {
        float* kc   = smem;          // 1024
        float* vc   = smem + 1024;   // 1024
        float* wred = smem + 2048;   // 8
        const int b  = bid >> 8;
        const int h  = (bid >> 2) & 63;
        const int qc = bid & 3;
        const size_t base = (size_t)(b * 64 + h) * 1024;

        float kmx = -1e30f, kmn = 1e30f;
        #pragma unroll
        for (int i = 0; i < 4; ++i) {
            float kv = kT[base + i * 256 + t];
            float vv = vT[base + i * 256 + t];
            kc[i * 256 + t] = kv;
            vc[i * 256 + t] = vv;
            kmx = fmaxf(kmx, kv);
            kmn = fminf(kmn, kv);
        }
        #pragma unroll
        for (int off = 32; off >= 1; off >>= 1) {
            kmx = fmaxf(kmx, __shfl_xor(kmx, off));
            kmn = fminf(kmn, __shfl_xor(kmn, off));
        }
        const int wid = t >> 6;
        if ((t & 63) == 0) { wred[wid] = kmx; wred[4 + wid] = kmn; }
        __syncthreads();
        kmx = fmaxf(fmaxf(wred[0], wred[1]), fmaxf(wred[2], wred[3]));
        kmn = fminf(fminf(wred[4], wred[5]), fminf(wred[6], wred[7]));

        const float qs = qT[base + qc * 256 + t];
        const float m  = (qs >= 0.f) ? qs * kmx : qs * kmn;
        const float a  = qs * LOG2E;
        const float bb = -m * LOG2E;

        float d0 = 0.f, d1 = 0.f, d2 = 0.f, d3 = 0.f;
        float n0 = 0.f, n1 = 0.f, n2 = 0.f, n3 = 0.f;
        const float4* kc4 = (const float4*)kc;
        const float4* vc4 = (const float4*)vc;
        for (int j = 0; j < 256; ++j) {
            float4 k4 = kc4[j];
            float4 v4 = vc4[j];
            float e0 = fast_exp2(fmaf(a, k4.x, bb));
            float e1 = fast_exp2(fmaf(a, k4.y, bb));
            float e2 = fast_exp2(fmaf(a, k4.z, bb));
            float e3 = fast_exp2(fmaf(a, k4.w, bb));
            d0 += e0; n0 = fmaf(e0, v4.x, n0);
            d1 += e1; n1 = fmaf(e1, v4.y, n1);
            d2 += e2; n2 = fmaf(e2, v4.z, n2);
            d3 += e3; n3 = fmaf(e3, v4.w, n3);
        }
        const float den = (d0 + d1) + (d2 + d3);
        const float num = (n0 + n1) + (n2 + n3);
        const int q = qc * 256 + t;
        O[(size_t)(b * 1024 + q) * 64 + h] = num / den;
    }

    grid.sync();   // O visible device-wide

    // ---------------- Phase 3: out = O @ Wo + bo (4 rows/block) ----------------
    {
        float* so = smem;                 // 4 rows x 64
        const size_t r0 = (size_t)bid * 4;
        so[t] = O[r0 * 64 + t];           // 256 floats, coalesced
        __syncthreads();

        const int d2 = t * 2;
        float2 bv = *(const float2*)&bo[d2];
        float acc0[4], acc1[4];
        #pragma unroll
        for (int r = 0; r < 4; ++r) { acc0[r] = bv.x; acc1[r] = bv.y; }
        for (int hh = 0; hh < 64; hh += 4) {
            float2 w0 = *(const float2*)&Wo[(hh + 0) * 512 + d2];
            float2 w1 = *(const float2*)&Wo[(hh + 1) * 512 + d2];
            float2 w2 = *(const float2*)&Wo[(hh + 2) * 512 + d2];
            float2 w3 = *(const float2*)&Wo[(hh + 3) * 512 + d2];
            #pragma unroll
            for (int r = 0; r < 4; ++r) {
                float4 s4 = *(const float4*)&so[r * 64 + hh];
                acc0[r] = fmaf(s4.x, w0.x, acc0[r]); acc1[r] = fmaf(s4.x, w0.y, acc1[r]);
                acc0[r] = fmaf(s4.y, w1.x, acc0[r]); acc1[r] = fmaf(s4.y, w1.y, acc1[r]);
                acc0[r] = fmaf(s4.z, w2.x, acc0[r]); acc1[r] = fmaf(s4.z, w2.y, acc1[r]);
                acc0[r] = fmaf(s4.w, w3.x, acc0[r]); acc1[r] = fmaf(s4.w, w3.y, acc1[r]);
            }
        }
        #pragma unroll
        for (int r = 0; r < 4; ++r)
            *(float2*)&out[(r0 + r) * 512 + d2] = make_float2(acc0[r], acc1[r]);
    }
}

extern "C" void kernel_launch(void* const* d_in, const int* in_sizes, int n_in,
                              void* d_out, int out_size, void* d_ws, size_t ws_size,
                              hipStream_t stream)
{
    const float* x   = (const float*)d_in[0];
    const float* emb = (const float*)d_in[1];
    const float* Wq  = (const float*)d_in[2];
    const float* Wk  = (const float*)d_in[3];
    const float* Wv  = (const float*)d_in[4];
    const float* Wo  = (const float*)d_in[5];
    const float* bo  = (const float*)d_in[6];
    float* out = (float*)d_out;

    // workspace: qT/kT/vT [B,64,1024] transposed + O [B,1024,64] — 2 MB total
    float* qT = (float*)d_ws;
    float* kT = qT + 131072;
    float* vT = kT + 131072;
    float* O  = vT + 131072;

    void* args[] = {
        (void*)&x, (void*)&emb, (void*)&Wq, (void*)&Wk, (void*)&Wv,
        (void*)&Wo, (void*)&bo, (void*)&out,
        (void*)&qT, (void*)&kT, (void*)&vT, (void*)&O
    };
    hipLaunchCooperativeKernel((const void*)fused_kernel,
                               dim3(512), dim3(256), args, 0, stream);
}

// Round 2
// 120.246 us; speedup vs baseline: 2.0797x; 2.0797x over previous
//
#include <hip/hip_runtime.h>
#include <hip/hip_bf16.h>

#define LOG2E 1.44269504088896340736f

__device__ __forceinline__ float fast_exp2(float x) {
#if __has_builtin(__builtin_amdgcn_exp2f)
    return __builtin_amdgcn_exp2f(x);
#else
    return exp2f(x);
#endif
}

// ---------------------------------------------------------------------------
// Stage 1: fused QKV projection with transposed outputs.
// grid = 512 blocks x 256 threads.
//   bid <  256 : Q path — rows rb*8..rb*8+7 of x   -> qT[b][h][q]
//   bid >= 256 : KV path — rows rb*8..rb*8+7 of emb -> kT[b][h][j], vT[b][h][j]
// ---------------------------------------------------------------------------
__global__ __launch_bounds__(256) void proj_kernel(
    const float* __restrict__ x, const float* __restrict__ emb,
    const float* __restrict__ Wq, const float* __restrict__ Wk,
    const float* __restrict__ Wv,
    float* __restrict__ qT, float* __restrict__ kT, float* __restrict__ vT)
{
    __shared__ __align__(16) float sx[4096];    // 8 rows x 512
    __shared__ __align__(16) float sred[4096];  // partial-sum reduction buffer
    const int t   = threadIdx.x;
    const int bid = blockIdx.x;
    const bool isQ = (bid < 256);
    const int rb  = isQ ? bid : (bid - 256);

    const float* src = (isQ ? x : emb) + (size_t)rb * 8 * 512;
    #pragma unroll
    for (int i = 0; i < 16; ++i) sx[i * 256 + t] = src[i * 256 + t];
    __syncthreads();

    const int b  = rb >> 7;          // rows rb*8 -> batch
    const int q0 = (rb << 3) & 1023; // seq offset

    if (isQ) {
        const int cp = (t & 31) * 2;
        const int g  = t >> 5;
        const int d0 = g * 64;
        float acc0[8], acc1[8];
        #pragma unroll
        for (int r = 0; r < 8; ++r) { acc0[r] = 0.f; acc1[r] = 0.f; }
        for (int dd = 0; dd < 64; dd += 4) {
            const int d = d0 + dd;
            float2 w0 = *(const float2*)&Wq[(d + 0) * 64 + cp];
            float2 w1 = *(const float2*)&Wq[(d + 1) * 64 + cp];
            float2 w2 = *(const float2*)&Wq[(d + 2) * 64 + cp];
            float2 w3 = *(const float2*)&Wq[(d + 3) * 64 + cp];
            #pragma unroll
            for (int r = 0; r < 8; ++r) {
                float4 xv = *(const float4*)&sx[r * 512 + d];
                acc0[r] = fmaf(xv.x, w0.x, acc0[r]); acc1[r] = fmaf(xv.x, w0.y, acc1[r]);
                acc0[r] = fmaf(xv.y, w1.x, acc0[r]); acc1[r] = fmaf(xv.y, w1.y, acc1[r]);
                acc0[r] = fmaf(xv.z, w2.x, acc0[r]); acc1[r] = fmaf(xv.z, w2.y, acc1[r]);
                acc0[r] = fmaf(xv.w, w3.x, acc0[r]); acc1[r] = fmaf(xv.w, w3.y, acc1[r]);
            }
        }
        #pragma unroll
        for (int r = 0; r < 8; ++r)
            *(float2*)&sred[g * 512 + r * 64 + cp] = make_float2(acc0[r], acc1[r]);
        __syncthreads();
        #pragma unroll
        for (int p = 0; p < 2; ++p) {
            int idx = p * 256 + t;
            int r = idx >> 6, h = idx & 63;
            float s = 0.f;
            #pragma unroll
            for (int g2 = 0; g2 < 8; ++g2) s += sred[g2 * 512 + r * 64 + h];
            qT[(size_t)(b * 64 + h) * 1024 + q0 + r] = s;
        }
    } else {
        const int cp = (t & 63) * 2;
        const int g  = t >> 6;
        const int d0 = g * 128;
        const float* Wsel = (cp < 64) ? (Wk + cp) : (Wv + (cp - 64));
        float acc0[8], acc1[8];
        #pragma unroll
        for (int r = 0; r < 8; ++r) { acc0[r] = 0.f; acc1[r] = 0.f; }
        for (int dd = 0; dd < 128; dd += 4) {
            const int d = d0 + dd;
            float2 w0 = *(const float2*)&Wsel[(d + 0) * 64];
            float2 w1 = *(const float2*)&Wsel[(d + 1) * 64];
            float2 w2 = *(const float2*)&Wsel[(d + 2) * 64];
            float2 w3 = *(const float2*)&Wsel[(d + 3) * 64];
            #pragma unroll
            for (int r = 0; r < 8; ++r) {
                float4 xv = *(const float4*)&sx[r * 512 + d];
                acc0[r] = fmaf(xv.x, w0.x, acc0[r]); acc1[r] = fmaf(xv.x, w0.y, acc1[r]);
                acc0[r] = fmaf(xv.y, w1.x, acc0[r]); acc1[r] = fmaf(xv.y, w1.y, acc1[r]);
                acc0[r] = fmaf(xv.z, w2.x, acc0[r]); acc1[r] = fmaf(xv.z, w2.y, acc1[r]);
                acc0[r] = fmaf(xv.w, w3.x, acc0[r]); acc1[r] = fmaf(xv.w, w3.y, acc1[r]);
            }
        }
        #pragma unroll
        for (int r = 0; r < 8; ++r)
            *(float2*)&sred[g * 1024 + r * 128 + cp] = make_float2(acc0[r], acc1[r]);
        __syncthreads();
        #pragma unroll
        for (int p = 0; p < 4; ++p) {
            int idx = p * 256 + t;
            int r = idx >> 7, c = idx & 127;
            float s = 0.f;
            #pragma unroll
            for (int g2 = 0; g2 < 4; ++g2) s += sred[g2 * 1024 + r * 128 + c];
            if (c < 64) kT[(size_t)(b * 64 + c) * 1024 + q0 + r] = s;
            else        vT[(size_t)(b * 64 + (c - 64)) * 1024 + q0 + r] = s;
        }
    }
}

// ---------------------------------------------------------------------------
// Stage 2: attention, head_dim==1.
// grid = B*64*4 = 512 blocks (b, h, q-chunk of 256), 256 threads (one q each).
// k/v inner-loop reads use WAVE-UNIFORM global addresses (base from blockIdx,
// j loop-uniform) on const __restrict__ pointers -> hipcc scalarizes them to
// s_load (SMEM pipe). This removes the LDS staging, which was the bottleneck:
// ds_read_b128 costs ~12 cyc/CU regardless of broadcast (register-write-BW
// bound), totalling ~20 us across the grid; SMEM runs parallel to VALU.
// Exact softmax stabilization via block-wide kmax/kmin (unchanged math).
// ---------------------------------------------------------------------------
__global__ __launch_bounds__(256) void attn_kernel(
    const float* __restrict__ qT, const float* __restrict__ kT,
    const float* __restrict__ vT, float* __restrict__ O)
{
    __shared__ float wred[8];
    const int t   = threadIdx.x;
    const int bid = blockIdx.x;
    const int b   = bid >> 8;
    const int h   = (bid >> 2) & 63;
    const int qc  = bid & 3;
    const size_t base = (size_t)(b * 64 + h) * 1024;

    // block-wide k max/min (per-lane coalesced reads; no LDS staging needed)
    float kmx = -1e30f, kmn = 1e30f;
    #pragma unroll
    for (int i = 0; i < 4; ++i) {
        float kv = kT[base + i * 256 + t];
        kmx = fmaxf(kmx, kv);
        kmn = fminf(kmn, kv);
    }
    #pragma unroll
    for (int off = 32; off >= 1; off >>= 1) {
        kmx = fmaxf(kmx, __shfl_xor(kmx, off));
        kmn = fminf(kmn, __shfl_xor(kmn, off));
    }
    const int wid = t >> 6;
    if ((t & 63) == 0) { wred[wid] = kmx; wred[4 + wid] = kmn; }
    __syncthreads();
    kmx = fmaxf(fmaxf(wred[0], wred[1]), fmaxf(wred[2], wred[3]));
    kmn = fminf(fminf(wred[4], wred[5]), fminf(wred[6], wred[7]));

    const float qs = qT[base + qc * 256 + t];           // coalesced
    const float m  = (qs >= 0.f) ? qs * kmx : qs * kmn; // exact row max of scores
    const float a  = qs * LOG2E;
    const float bb = -m * LOG2E;

    float d0 = 0.f, d1 = 0.f, d2 = 0.f, d3 = 0.f;
    float n0 = 0.f, n1 = 0.f, n2 = 0.f, n3 = 0.f;
    const float* kp = kT + base;   // wave-uniform base
    const float* vp = vT + base;
    #pragma unroll 4
    for (int j = 0; j < 1024; j += 4) {
        float4 k4 = *(const float4*)&kp[j];   // uniform addr -> s_load
        float4 v4 = *(const float4*)&vp[j];
        float e0 = fast_exp2(fmaf(a, k4.x, bb));
        float e1 = fast_exp2(fmaf(a, k4.y, bb));
        float e2 = fast_exp2(fmaf(a, k4.z, bb));
        float e3 = fast_exp2(fmaf(a, k4.w, bb));
        d0 += e0; n0 = fmaf(e0, v4.x, n0);
        d1 += e1; n1 = fmaf(e1, v4.y, n1);
        d2 += e2; n2 = fmaf(e2, v4.z, n2);
        d3 += e3; n3 = fmaf(e3, v4.w, n3);
    }
    const float den = (d0 + d1) + (d2 + d3);
    const float num = (n0 + n1) + (n2 + n3);
    const int q = qc * 256 + t;
    O[(size_t)(b * 1024 + q) * 64 + h] = num / den;   // [b,q,h] layout for stage 3
}

// ---------------------------------------------------------------------------
// Stage 3: out = O @ Wo + bo.  [2048x64]@[64x512].
// grid = 256 blocks (8 rows each), 256 threads (2 output cols each).
// ---------------------------------------------------------------------------
__global__ __launch_bounds__(256) void oproj_kernel(
    const float* __restrict__ O, const float* __restrict__ Wo,
    const float* __restrict__ bo, float* __restrict__ out)
{
    __shared__ __align__(16) float so[512];   // 8 rows x 64
    const int t  = threadIdx.x;
    const int rb = blockIdx.x;
    const size_t r0 = (size_t)rb * 8;
    so[t]       = O[r0 * 64 + t];
    so[t + 256] = O[r0 * 64 + t + 256];
    __syncthreads();

    const int d2 = t * 2;
    float2 bv = *(const float2*)&bo[d2];
    float acc0[8], acc1[8];
    #pragma unroll
    for (int r = 0; r < 8; ++r) { acc0[r] = bv.x; acc1[r] = bv.y; }
    for (int hh = 0; hh < 64; hh += 4) {
        float2 w0 = *(const float2*)&Wo[(hh + 0) * 512 + d2];
        float2 w1 = *(const float2*)&Wo[(hh + 1) * 512 + d2];
        float2 w2 = *(const float2*)&Wo[(hh + 2) * 512 + d2];
        float2 w3 = *(const float2*)&Wo[(hh + 3) * 512 + d2];
        #pragma unroll
        for (int r = 0; r < 8; ++r) {
            float4 s4 = *(const float4*)&so[r * 64 + hh];
            acc0[r] = fmaf(s4.x, w0.x, acc0[r]); acc1[r] = fmaf(s4.x, w0.y, acc1[r]);
            acc0[r] = fmaf(s4.y, w1.x, acc0[r]); acc1[r] = fmaf(s4.y, w1.y, acc1[r]);
            acc0[r] = fmaf(s4.z, w2.x, acc0[r]); acc1[r] = fmaf(s4.z, w2.y, acc1[r]);
            acc0[r] = fmaf(s4.w, w3.x, acc0[r]); acc1[r] = fmaf(s4.w, w3.y, acc1[r]);
        }
    }
    #pragma unroll
    for (int r = 0; r < 8; ++r)
        *(float2*)&out[(r0 + r) * 512 + d2] = make_float2(acc0[r], acc1[r]);
}

extern "C" void kernel_launch(void* const* d_in, const int* in_sizes, int n_in,
                              void* d_out, int out_size, void* d_ws, size_t ws_size,
                              hipStream_t stream)
{
    const float* x   = (const float*)d_in[0];
    const float* emb = (const float*)d_in[1];
    const float* Wq  = (const float*)d_in[2];
    const float* Wk  = (const float*)d_in[3];
    const float* Wv  = (const float*)d_in[4];
    const float* Wo  = (const float*)d_in[5];
    const float* bo  = (const float*)d_in[6];
    float* out = (float*)d_out;

    // workspace: qT/kT/vT [B,64,1024] transposed + O [B,1024,64] — 2 MB total
    float* qT = (float*)d_ws;
    float* kT = qT + 131072;
    float* vT = kT + 131072;
    float* O  = vT + 131072;

    proj_kernel<<<512, 256, 0, stream>>>(x, emb, Wq, Wk, Wv, qT, kT, vT);
    attn_kernel<<<512, 256, 0, stream>>>(qT, kT, vT, O);
    oproj_kernel<<<256, 256, 0, stream>>>(O, Wo, bo, out);
}

// Round 5
// 113.349 us; speedup vs baseline: 2.2062x; 1.0608x over previous
//
#include <hip/hip_runtime.h>
#include <hip/hip_bf16.h>

#define LOG2E 1.44269504088896340736f

__device__ __forceinline__ float fast_exp2(float x) {
#if __has_builtin(__builtin_amdgcn_exp2f)
    return __builtin_amdgcn_exp2f(x);
#else
    return exp2f(x);
#endif
}

// ---------------------------------------------------------------------------
// Stage 1: fused QKV projection with transposed outputs (identical to the
// verified 109.9us version).
// ---------------------------------------------------------------------------
__global__ __launch_bounds__(256) void proj_kernel(
    const float* __restrict__ x, const float* __restrict__ emb,
    const float* __restrict__ Wq, const float* __restrict__ Wk,
    const float* __restrict__ Wv,
    float* __restrict__ qT, float* __restrict__ kT, float* __restrict__ vT)
{
    __shared__ __align__(16) float sx[4096];    // 8 rows x 512
    __shared__ __align__(16) float sred[4096];  // partial-sum reduction buffer
    const int t   = threadIdx.x;
    const int bid = blockIdx.x;
    const bool isQ = (bid < 256);
    const int rb  = isQ ? bid : (bid - 256);

    const float* src = (isQ ? x : emb) + (size_t)rb * 8 * 512;
    #pragma unroll
    for (int i = 0; i < 16; ++i) sx[i * 256 + t] = src[i * 256 + t];
    __syncthreads();

    const int b  = rb >> 7;          // rows rb*8 -> batch
    const int q0 = (rb << 3) & 1023; // seq offset

    if (isQ) {
        const int cp = (t & 31) * 2;
        const int g  = t >> 5;
        const int d0 = g * 64;
        float acc0[8], acc1[8];
        #pragma unroll
        for (int r = 0; r < 8; ++r) { acc0[r] = 0.f; acc1[r] = 0.f; }
        for (int dd = 0; dd < 64; dd += 4) {
            const int d = d0 + dd;
            float2 w0 = *(const float2*)&Wq[(d + 0) * 64 + cp];
            float2 w1 = *(const float2*)&Wq[(d + 1) * 64 + cp];
            float2 w2 = *(const float2*)&Wq[(d + 2) * 64 + cp];
            float2 w3 = *(const float2*)&Wq[(d + 3) * 64 + cp];
            #pragma unroll
            for (int r = 0; r < 8; ++r) {
                float4 xv = *(const float4*)&sx[r * 512 + d];
                acc0[r] = fmaf(xv.x, w0.x, acc0[r]); acc1[r] = fmaf(xv.x, w0.y, acc1[r]);
                acc0[r] = fmaf(xv.y, w1.x, acc0[r]); acc1[r] = fmaf(xv.y, w1.y, acc1[r]);
                acc0[r] = fmaf(xv.z, w2.x, acc0[r]); acc1[r] = fmaf(xv.z, w2.y, acc1[r]);
                acc0[r] = fmaf(xv.w, w3.x, acc0[r]); acc1[r] = fmaf(xv.w, w3.y, acc1[r]);
            }
        }
        #pragma unroll
        for (int r = 0; r < 8; ++r)
            *(float2*)&sred[g * 512 + r * 64 + cp] = make_float2(acc0[r], acc1[r]);
        __syncthreads();
        #pragma unroll
        for (int p = 0; p < 2; ++p) {
            int idx = p * 256 + t;
            int r = idx >> 6, h = idx & 63;
            float s = 0.f;
            #pragma unroll
            for (int g2 = 0; g2 < 8; ++g2) s += sred[g2 * 512 + r * 64 + h];
            qT[(size_t)(b * 64 + h) * 1024 + q0 + r] = s;
        }
    } else {
        const int cp = (t & 63) * 2;
        const int g  = t >> 6;
        const int d0 = g * 128;
        const float* Wsel = (cp < 64) ? (Wk + cp) : (Wv + (cp - 64));
        float acc0[8], acc1[8];
        #pragma unroll
        for (int r = 0; r < 8; ++r) { acc0[r] = 0.f; acc1[r] = 0.f; }
        for (int dd = 0; dd < 128; dd += 4) {
            const int d = d0 + dd;
            float2 w0 = *(const float2*)&Wsel[(d + 0) * 64];
            float2 w1 = *(const float2*)&Wsel[(d + 1) * 64];
            float2 w2 = *(const float2*)&Wsel[(d + 2) * 64];
            float2 w3 = *(const float2*)&Wsel[(d + 3) * 64];
            #pragma unroll
            for (int r = 0; r < 8; ++r) {
                float4 xv = *(const float4*)&sx[r * 512 + d];
                acc0[r] = fmaf(xv.x, w0.x, acc0[r]); acc1[r] = fmaf(xv.x, w0.y, acc1[r]);
                acc0[r] = fmaf(xv.y, w1.x, acc0[r]); acc1[r] = fmaf(xv.y, w1.y, acc1[r]);
                acc0[r] = fmaf(xv.z, w2.x, acc0[r]); acc1[r] = fmaf(xv.z, w2.y, acc1[r]);
                acc0[r] = fmaf(xv.w, w3.x, acc0[r]); acc1[r] = fmaf(xv.w, w3.y, acc1[r]);
            }
        }
        #pragma unroll
        for (int r = 0; r < 8; ++r)
            *(float2*)&sred[g * 1024 + r * 128 + cp] = make_float2(acc0[r], acc1[r]);
        __syncthreads();
        #pragma unroll
        for (int p = 0; p < 4; ++p) {
            int idx = p * 256 + t;
            int r = idx >> 7, c = idx & 127;
            float s = 0.f;
            #pragma unroll
            for (int g2 = 0; g2 < 4; ++g2) s += sred[g2 * 1024 + r * 128 + c];
            if (c < 64) kT[(size_t)(b * 64 + c) * 1024 + q0 + r] = s;
            else        vT[(size_t)(b * 64 + (c - 64)) * 1024 + q0 + r] = s;
        }
    }
}

// ---------------------------------------------------------------------------
// Stage 2: attention, head_dim==1, TWO q-rows per thread.
// grid = B*64*2 = 256 blocks (b, h, q-half of 512), 256 threads.
// Thread t handles q = qh*512 + t and q + 256. Each k4/v4 LDS read is
// amortized over both rows, HALVING the ds_read_b128 stream that bounds the
// kernel (1M -> 524K instrs; ~20.5us -> ~10.2us LDS-pipe time). Trans-pipe
// (6.8us of v_exp) and VALU (5.1us) overlap beneath it. 8 independent exp
// chains per iteration give ILP at 1 wave/SIMD.
// Per-q accumulation order (element E -> accumulator E&3, increasing j) is
// IDENTICAL to the verified kernel -> per-q results bitwise unchanged.
// ---------------------------------------------------------------------------
__global__ __launch_bounds__(256) void attn_kernel(
    const float* __restrict__ qT, const float* __restrict__ kT,
    const float* __restrict__ vT, float* __restrict__ O)
{
    __shared__ __align__(16) float kc[1024];
    __shared__ __align__(16) float vc[1024];
    __shared__ float wred[8];
    const int t   = threadIdx.x;
    const int bid = blockIdx.x;
    const int b   = bid >> 7;          // 128 (h,qh) combos per batch
    const int h   = (bid >> 1) & 63;
    const int qh  = bid & 1;           // q-half: rows qh*512 .. qh*512+511
    const size_t base = (size_t)(b * 64 + h) * 1024;

    float kmx = -1e30f, kmn = 1e30f;
    #pragma unroll
    for (int i = 0; i < 4; ++i) {
        float kv = kT[base + i * 256 + t];
        float vv = vT[base + i * 256 + t];
        kc[i * 256 + t] = kv;
        vc[i * 256 + t] = vv;
        kmx = fmaxf(kmx, kv);
        kmn = fminf(kmn, kv);
    }
    #pragma unroll
    for (int off = 32; off >= 1; off >>= 1) {
        kmx = fmaxf(kmx, __shfl_xor(kmx, off));
        kmn = fminf(kmn, __shfl_xor(kmn, off));
    }
    const int wid = t >> 6;
    if ((t & 63) == 0) { wred[wid] = kmx; wred[4 + wid] = kmn; }
    __syncthreads();
    kmx = fmaxf(fmaxf(wred[0], wred[1]), fmaxf(wred[2], wred[3]));
    kmn = fminf(fminf(wred[4], wred[5]), fminf(wred[6], wred[7]));

    // two q rows per thread (both reads coalesced)
    const int qa = qh * 512 + t;
    const int qb = qa + 256;
    const float qsa = qT[base + qa];
    const float qsb = qT[base + qb];
    const float ma  = (qsa >= 0.f) ? qsa * kmx : qsa * kmn;
    const float mb  = (qsb >= 0.f) ? qsb * kmx : qsb * kmn;
    const float aa  = qsa * LOG2E;
    const float ab  = qsb * LOG2E;
    const float ba  = -ma * LOG2E;
    const float bb  = -mb * LOG2E;

    float da0 = 0.f, da1 = 0.f, da2 = 0.f, da3 = 0.f;
    float na0 = 0.f, na1 = 0.f, na2 = 0.f, na3 = 0.f;
    float db0 = 0.f, db1 = 0.f, db2 = 0.f, db3 = 0.f;
    float nb0 = 0.f, nb1 = 0.f, nb2 = 0.f, nb3 = 0.f;
    const float4* kc4 = (const float4*)kc;
    const float4* vc4 = (const float4*)vc;
    for (int j = 0; j < 256; ++j) {
        float4 k4 = kc4[j];
        float4 v4 = vc4[j];
        float ea0 = fast_exp2(fmaf(aa, k4.x, ba));
        float ea1 = fast_exp2(fmaf(aa, k4.y, ba));
        float ea2 = fast_exp2(fmaf(aa, k4.z, ba));
        float ea3 = fast_exp2(fmaf(aa, k4.w, ba));
        float eb0 = fast_exp2(fmaf(ab, k4.x, bb));
        float eb1 = fast_exp2(fmaf(ab, k4.y, bb));
        float eb2 = fast_exp2(fmaf(ab, k4.z, bb));
        float eb3 = fast_exp2(fmaf(ab, k4.w, bb));
        da0 += ea0; na0 = fmaf(ea0, v4.x, na0);
        da1 += ea1; na1 = fmaf(ea1, v4.y, na1);
        da2 += ea2; na2 = fmaf(ea2, v4.z, na2);
        da3 += ea3; na3 = fmaf(ea3, v4.w, na3);
        db0 += eb0; nb0 = fmaf(eb0, v4.x, nb0);
        db1 += eb1; nb1 = fmaf(eb1, v4.y, nb1);
        db2 += eb2; nb2 = fmaf(eb2, v4.z, nb2);
        db3 += eb3; nb3 = fmaf(eb3, v4.w, nb3);
    }
    const float dena = (da0 + da1) + (da2 + da3);
    const float numa = (na0 + na1) + (na2 + na3);
    const float denb = (db0 + db1) + (db2 + db3);
    const float numb = (nb0 + nb1) + (nb2 + nb3);
    O[(size_t)(b * 1024 + qa) * 64 + h] = numa / dena;   // [b,q,h] layout
    O[(size_t)(b * 1024 + qb) * 64 + h] = numb / denb;
}

// ---------------------------------------------------------------------------
// Stage 3: out = O @ Wo + bo.  [2048x64]@[64x512].
// grid = 256 blocks (8 rows each), 256 threads (2 output cols each).
// ---------------------------------------------------------------------------
__global__ __launch_bounds__(256) void oproj_kernel(
    const float* __restrict__ O, const float* __restrict__ Wo,
    const float* __restrict__ bo, float* __restrict__ out)
{
    __shared__ __align__(16) float so[512];   // 8 rows x 64
    const int t  = threadIdx.x;
    const int rb = blockIdx.x;
    const size_t r0 = (size_t)rb * 8;
    so[t]       = O[r0 * 64 + t];
    so[t + 256] = O[r0 * 64 + t + 256];
    __syncthreads();

    const int d2 = t * 2;
    float2 bv = *(const float2*)&bo[d2];
    float acc0[8], acc1[8];
    #pragma unroll
    for (int r = 0; r < 8; ++r) { acc0[r] = bv.x; acc1[r] = bv.y; }
    for (int hh = 0; hh < 64; hh += 4) {
        float2 w0 = *(const float2*)&Wo[(hh + 0) * 512 + d2];
        float2 w1 = *(const float2*)&Wo[(hh + 1) * 512 + d2];
        float2 w2 = *(const float2*)&Wo[(hh + 2) * 512 + d2];
        float2 w3 = *(const float2*)&Wo[(hh + 3) * 512 + d2];
        #pragma unroll
        for (int r = 0; r < 8; ++r) {
            float4 s4 = *(const float4*)&so[r * 64 + hh];
            acc0[r] = fmaf(s4.x, w0.x, acc0[r]); acc1[r] = fmaf(s4.x, w0.y, acc1[r]);
            acc0[r] = fmaf(s4.y, w1.x, acc0[r]); acc1[r] = fmaf(s4.y, w1.y, acc1[r]);
            acc0[r] = fmaf(s4.z, w2.x, acc0[r]); acc1[r] = fmaf(s4.z, w2.y, acc1[r]);
            acc0[r] = fmaf(s4.w, w3.x, acc0[r]); acc1[r] = fmaf(s4.w, w3.y, acc1[r]);
        }
    }
    #pragma unroll
    for (int r = 0; r < 8; ++r)
        *(float2*)&out[(r0 + r) * 512 + d2] = make_float2(acc0[r], acc1[r]);
}

extern "C" void kernel_launch(void* const* d_in, const int* in_sizes, int n_in,
                              void* d_out, int out_size, void* d_ws, size_t ws_size,
                              hipStream_t stream)
{
    const float* x   = (const float*)d_in[0];
    const float* emb = (const float*)d_in[1];
    const float* Wq  = (const float*)d_in[2];
    const float* Wk  = (const float*)d_in[3];
    const float* Wv  = (const float*)d_in[4];
    const float* Wo  = (const float*)d_in[5];
    const float* bo  = (const float*)d_in[6];
    float* out = (float*)d_out;

    // workspace: qT/kT/vT [B,64,1024] transposed + O [B,1024,64] — 2 MB total
    float* qT = (float*)d_ws;
    float* kT = qT + 131072;
    float* vT = kT + 131072;
    float* O  = vT + 131072;

    proj_kernel<<<512, 256, 0, stream>>>(x, emb, Wq, Wk, Wv, qT, kT, vT);
    attn_kernel<<<256, 256, 0, stream>>>(qT, kT, vT, O);
    oproj_kernel<<<256, 256, 0, stream>>>(O, Wo, bo, out);
}

// Round 6
// 110.188 us; speedup vs baseline: 2.2695x; 1.0287x over previous
//
#include <hip/hip_runtime.h>
#include <hip/hip_bf16.h>

#define LOG2E 1.44269504088896340736f

__device__ __forceinline__ float fast_exp2(float x) {
#if __has_builtin(__builtin_amdgcn_exp2f)
    return __builtin_amdgcn_exp2f(x);
#else
    return exp2f(x);
#endif
}

// ---------------------------------------------------------------------------
// Stage 1: fused QKV projection with transposed outputs (identical to the
// verified 109.9us version).
// ---------------------------------------------------------------------------
__global__ __launch_bounds__(256) void proj_kernel(
    const float* __restrict__ x, const float* __restrict__ emb,
    const float* __restrict__ Wq, const float* __restrict__ Wk,
    const float* __restrict__ Wv,
    float* __restrict__ qT, float* __restrict__ kT, float* __restrict__ vT)
{
    __shared__ __align__(16) float sx[4096];    // 8 rows x 512
    __shared__ __align__(16) float sred[4096];  // partial-sum reduction buffer
    const int t   = threadIdx.x;
    const int bid = blockIdx.x;
    const bool isQ = (bid < 256);
    const int rb  = isQ ? bid : (bid - 256);

    const float* src = (isQ ? x : emb) + (size_t)rb * 8 * 512;
    #pragma unroll
    for (int i = 0; i < 16; ++i) sx[i * 256 + t] = src[i * 256 + t];
    __syncthreads();

    const int b  = rb >> 7;          // rows rb*8 -> batch
    const int q0 = (rb << 3) & 1023; // seq offset

    if (isQ) {
        const int cp = (t & 31) * 2;
        const int g  = t >> 5;
        const int d0 = g * 64;
        float acc0[8], acc1[8];
        #pragma unroll
        for (int r = 0; r < 8; ++r) { acc0[r] = 0.f; acc1[r] = 0.f; }
        for (int dd = 0; dd < 64; dd += 4) {
            const int d = d0 + dd;
            float2 w0 = *(const float2*)&Wq[(d + 0) * 64 + cp];
            float2 w1 = *(const float2*)&Wq[(d + 1) * 64 + cp];
            float2 w2 = *(const float2*)&Wq[(d + 2) * 64 + cp];
            float2 w3 = *(const float2*)&Wq[(d + 3) * 64 + cp];
            #pragma unroll
            for (int r = 0; r < 8; ++r) {
                float4 xv = *(const float4*)&sx[r * 512 + d];
                acc0[r] = fmaf(xv.x, w0.x, acc0[r]); acc1[r] = fmaf(xv.x, w0.y, acc1[r]);
                acc0[r] = fmaf(xv.y, w1.x, acc0[r]); acc1[r] = fmaf(xv.y, w1.y, acc1[r]);
                acc0[r] = fmaf(xv.z, w2.x, acc0[r]); acc1[r] = fmaf(xv.z, w2.y, acc1[r]);
                acc0[r] = fmaf(xv.w, w3.x, acc0[r]); acc1[r] = fmaf(xv.w, w3.y, acc1[r]);
            }
        }
        #pragma unroll
        for (int r = 0; r < 8; ++r)
            *(float2*)&sred[g * 512 + r * 64 + cp] = make_float2(acc0[r], acc1[r]);
        __syncthreads();
        #pragma unroll
        for (int p = 0; p < 2; ++p) {
            int idx = p * 256 + t;
            int r = idx >> 6, h = idx & 63;
            float s = 0.f;
            #pragma unroll
            for (int g2 = 0; g2 < 8; ++g2) s += sred[g2 * 512 + r * 64 + h];
            qT[(size_t)(b * 64 + h) * 1024 + q0 + r] = s;
        }
    } else {
        const int cp = (t & 63) * 2;
        const int g  = t >> 6;
        const int d0 = g * 128;
        const float* Wsel = (cp < 64) ? (Wk + cp) : (Wv + (cp - 64));
        float acc0[8], acc1[8];
        #pragma unroll
        for (int r = 0; r < 8; ++r) { acc0[r] = 0.f; acc1[r] = 0.f; }
        for (int dd = 0; dd < 128; dd += 4) {
            const int d = d0 + dd;
            float2 w0 = *(const float2*)&Wsel[(d + 0) * 64];
            float2 w1 = *(const float2*)&Wsel[(d + 1) * 64];
            float2 w2 = *(const float2*)&Wsel[(d + 2) * 64];
            float2 w3 = *(const float2*)&Wsel[(d + 3) * 64];
            #pragma unroll
            for (int r = 0; r < 8; ++r) {
                float4 xv = *(const float4*)&sx[r * 512 + d];
                acc0[r] = fmaf(xv.x, w0.x, acc0[r]); acc1[r] = fmaf(xv.x, w0.y, acc1[r]);
                acc0[r] = fmaf(xv.y, w1.x, acc0[r]); acc1[r] = fmaf(xv.y, w1.y, acc1[r]);
                acc0[r] = fmaf(xv.z, w2.x, acc0[r]); acc1[r] = fmaf(xv.z, w2.y, acc1[r]);
                acc0[r] = fmaf(xv.w, w3.x, acc0[r]); acc1[r] = fmaf(xv.w, w3.y, acc1[r]);
            }
        }
        #pragma unroll
        for (int r = 0; r < 8; ++r)
            *(float2*)&sred[g * 1024 + r * 128 + cp] = make_float2(acc0[r], acc1[r]);
        __syncthreads();
        #pragma unroll
        for (int p = 0; p < 4; ++p) {
            int idx = p * 256 + t;
            int r = idx >> 7, c = idx & 127;
            float s = 0.f;
            #pragma unroll
            for (int g2 = 0; g2 < 4; ++g2) s += sred[g2 * 1024 + r * 128 + c];
            if (c < 64) kT[(size_t)(b * 64 + c) * 1024 + q0 + r] = s;
            else        vT[(size_t)(b * 64 + (c - 64)) * 1024 + q0 + r] = s;
        }
    }
}

// ---------------------------------------------------------------------------
// Stage 2: attention, head_dim==1. TWO q-rows per thread AND j-range split.
// grid = B*64*2*2 = 512 blocks: (b, h, q-half of 512, j-half of 512).
// This keeps round-5's halved ds_read_b128 stream (the qpt=2 win) while
// restoring 2 blocks/CU = 2 waves/SIMD (the occupancy round-5 lost, which
// cancelled the win: 1 wave/SIMD exposed LDS latency).
// Each block: stages its 512-element k/v slice, computes PARTIAL (num, den)
// for its 512 q-rows, writes them; oproj combines (nA+nB)/(dA+dB).
// m uses FULL-range kmax/kmin (all 1024 k read for the reduction), so every
// exp argument is bit-identical to the verified kernel; only the final
// halves-join of num/den is reassociated (13x absmax headroom).
// ---------------------------------------------------------------------------
__global__ __launch_bounds__(256) void attn_kernel(
    const float* __restrict__ qT, const float* __restrict__ kT,
    const float* __restrict__ vT, float* __restrict__ numP,
    float* __restrict__ denP)
{
    __shared__ __align__(16) float kc[512];
    __shared__ __align__(16) float vc[512];
    __shared__ float wred[8];
    const int t   = threadIdx.x;
    const int bid = blockIdx.x;
    const int b   = bid >> 8;
    const int h   = (bid >> 2) & 63;
    const int qh  = (bid >> 1) & 1;    // q-half: rows qh*512 .. +511
    const int jh  = bid & 1;           // j-half: cols jh*512 .. +511
    const size_t base = (size_t)(b * 64 + h) * 1024;

    // full-range k max/min (4 coalesced reads); stage only our j-slice
    float kmx = -1e30f, kmn = 1e30f;
    #pragma unroll
    for (int i = 0; i < 4; ++i) {
        float kv = kT[base + i * 256 + t];
        kmx = fmaxf(kmx, kv);
        kmn = fminf(kmn, kv);
        if ((i >> 1) == jh) kc[(i & 1) * 256 + t] = kv;
    }
    #pragma unroll
    for (int i2 = 0; i2 < 2; ++i2)
        vc[i2 * 256 + t] = vT[base + (jh * 2 + i2) * 256 + t];
    #pragma unroll
    for (int off = 32; off >= 1; off >>= 1) {
        kmx = fmaxf(kmx, __shfl_xor(kmx, off));
        kmn = fminf(kmn, __shfl_xor(kmn, off));
    }
    const int wid = t >> 6;
    if ((t & 63) == 0) { wred[wid] = kmx; wred[4 + wid] = kmn; }
    __syncthreads();
    kmx = fmaxf(fmaxf(wred[0], wred[1]), fmaxf(wred[2], wred[3]));
    kmn = fminf(fminf(wred[4], wred[5]), fminf(wred[6], wred[7]));

    // two q rows per thread (both reads coalesced)
    const int qa = qh * 512 + t;
    const int qb = qa + 256;
    const float qsa = qT[base + qa];
    const float qsb = qT[base + qb];
    const float ma  = (qsa >= 0.f) ? qsa * kmx : qsa * kmn;  // full-range row max
    const float mb  = (qsb >= 0.f) ? qsb * kmx : qsb * kmn;
    const float aa  = qsa * LOG2E;
    const float ab  = qsb * LOG2E;
    const float ba  = -ma * LOG2E;
    const float bb  = -mb * LOG2E;

    float da0 = 0.f, da1 = 0.f, da2 = 0.f, da3 = 0.f;
    float na0 = 0.f, na1 = 0.f, na2 = 0.f, na3 = 0.f;
    float db0 = 0.f, db1 = 0.f, db2 = 0.f, db3 = 0.f;
    float nb0 = 0.f, nb1 = 0.f, nb2 = 0.f, nb3 = 0.f;
    const float4* kc4 = (const float4*)kc;
    const float4* vc4 = (const float4*)vc;
    for (int j = 0; j < 128; ++j) {
        float4 k4 = kc4[j];
        float4 v4 = vc4[j];
        float ea0 = fast_exp2(fmaf(aa, k4.x, ba));
        float ea1 = fast_exp2(fmaf(aa, k4.y, ba));
        float ea2 = fast_exp2(fmaf(aa, k4.z, ba));
        float ea3 = fast_exp2(fmaf(aa, k4.w, ba));
        float eb0 = fast_exp2(fmaf(ab, k4.x, bb));
        float eb1 = fast_exp2(fmaf(ab, k4.y, bb));
        float eb2 = fast_exp2(fmaf(ab, k4.z, bb));
        float eb3 = fast_exp2(fmaf(ab, k4.w, bb));
        da0 += ea0; na0 = fmaf(ea0, v4.x, na0);
        da1 += ea1; na1 = fmaf(ea1, v4.y, na1);
        da2 += ea2; na2 = fmaf(ea2, v4.z, na2);
        da3 += ea3; na3 = fmaf(ea3, v4.w, na3);
        db0 += eb0; nb0 = fmaf(eb0, v4.x, nb0);
        db1 += eb1; nb1 = fmaf(eb1, v4.y, nb1);
        db2 += eb2; nb2 = fmaf(eb2, v4.z, nb2);
        db3 += eb3; nb3 = fmaf(eb3, v4.w, nb3);
    }
    const float dena = (da0 + da1) + (da2 + da3);
    const float numa = (na0 + na1) + (na2 + na3);
    const float denb = (db0 + db1) + (db2 + db3);
    const float numb = (nb0 + nb1) + (nb2 + nb3);
    // partial outputs: [jh][b*1024+q][h]
    const size_t pa = (size_t)jh * 131072 + (size_t)(b * 1024 + qa) * 64 + h;
    const size_t pb = (size_t)jh * 131072 + (size_t)(b * 1024 + qb) * 64 + h;
    numP[pa] = numa; denP[pa] = dena;
    numP[pb] = numb; denP[pb] = denb;
}

// ---------------------------------------------------------------------------
// Stage 3: combine j-half partials, then out = O @ Wo + bo.  [2048x64]@[64x512].
// grid = 256 blocks (8 rows each), 256 threads (2 output cols each).
// ---------------------------------------------------------------------------
__global__ __launch_bounds__(256) void oproj_kernel(
    const float* __restrict__ numP, const float* __restrict__ denP,
    const float* __restrict__ Wo, const float* __restrict__ bo,
    float* __restrict__ out)
{
    __shared__ __align__(16) float so[512];   // 8 rows x 64
    const int t  = threadIdx.x;
    const int rb = blockIdx.x;
    const size_t r0 = (size_t)rb * 8;
    #pragma unroll
    for (int p = 0; p < 2; ++p) {
        const size_t gi = r0 * 64 + p * 256 + t;
        float n = numP[gi] + numP[gi + 131072];
        float d = denP[gi] + denP[gi + 131072];
        so[p * 256 + t] = n / d;
    }
    __syncthreads();

    const int d2 = t * 2;
    float2 bv = *(const float2*)&bo[d2];
    float acc0[8], acc1[8];
    #pragma unroll
    for (int r = 0; r < 8; ++r) { acc0[r] = bv.x; acc1[r] = bv.y; }
    for (int hh = 0; hh < 64; hh += 4) {
        float2 w0 = *(const float2*)&Wo[(hh + 0) * 512 + d2];
        float2 w1 = *(const float2*)&Wo[(hh + 1) * 512 + d2];
        float2 w2 = *(const float2*)&Wo[(hh + 2) * 512 + d2];
        float2 w3 = *(const float2*)&Wo[(hh + 3) * 512 + d2];
        #pragma unroll
        for (int r = 0; r < 8; ++r) {
            float4 s4 = *(const float4*)&so[r * 64 + hh];
            acc0[r] = fmaf(s4.x, w0.x, acc0[r]); acc1[r] = fmaf(s4.x, w0.y, acc1[r]);
            acc0[r] = fmaf(s4.y, w1.x, acc0[r]); acc1[r] = fmaf(s4.y, w1.y, acc1[r]);
            acc0[r] = fmaf(s4.z, w2.x, acc0[r]); acc1[r] = fmaf(s4.z, w2.y, acc1[r]);
            acc0[r] = fmaf(s4.w, w3.x, acc0[r]); acc1[r] = fmaf(s4.w, w3.y, acc1[r]);
        }
    }
    #pragma unroll
    for (int r = 0; r < 8; ++r)
        *(float2*)&out[(r0 + r) * 512 + d2] = make_float2(acc0[r], acc1[r]);
}

extern "C" void kernel_launch(void* const* d_in, const int* in_sizes, int n_in,
                              void* d_out, int out_size, void* d_ws, size_t ws_size,
                              hipStream_t stream)
{
    const float* x   = (const float*)d_in[0];
    const float* emb = (const float*)d_in[1];
    const float* Wq  = (const float*)d_in[2];
    const float* Wk  = (const float*)d_in[3];
    const float* Wv  = (const float*)d_in[4];
    const float* Wo  = (const float*)d_in[5];
    const float* bo  = (const float*)d_in[6];
    float* out = (float*)d_out;

    // workspace: qT/kT/vT [B,64,1024] + numP/denP [2][B*1024][64] — 3.5 MB
    float* qT   = (float*)d_ws;
    float* kT   = qT + 131072;
    float* vT   = kT + 131072;
    float* numP = vT + 131072;
    float* denP = numP + 262144;

    proj_kernel<<<512, 256, 0, stream>>>(x, emb, Wq, Wk, Wv, qT, kT, vT);
    attn_kernel<<<512, 256, 0, stream>>>(qT, kT, vT, numP, denP);
    oproj_kernel<<<256, 256, 0, stream>>>(numP, denP, Wo, bo, out);
}